// Round 6
// baseline (1378.500 us; speedup 1.0000x reference)
//
#include <hip/hip_runtime.h>
#include <cstdint>

#define SEQ 2048
#define DM 768
#define NH 12
#define DKH 64
#define DFF 3072
#define NL 6
#define NTOK 4096   // B*S

typedef __attribute__((ext_vector_type(8))) short bf16x8;
typedef __attribute__((ext_vector_type(4))) float f32x4;

static __device__ __forceinline__ unsigned short f2b(float f) {
    unsigned int u = __builtin_bit_cast(unsigned int, f);
    unsigned int lsb = (u >> 16) & 1;
    u += 0x7fffu + lsb;                 // round-to-nearest-even
    return (unsigned short)(u >> 16);
}

static __device__ __forceinline__ unsigned int cvtpk2(float a, float b) {
    unsigned int r;
    asm("v_cvt_pk_bf16_f32 %0, %1, %2" : "=v"(r) : "v"(a), "v"(b));
    return r;                            // low16 = bf16(a), high16 = bf16(b)
}

// ---------------- embedding + positional encoding ----------------
__global__ __launch_bounds__(256) void embed_k(const int* __restrict__ tokens,
                                               const float* __restrict__ emb,
                                               float* __restrict__ x)
{
    int srow = blockIdx.y;
    int d = blockIdx.x * 256 + threadIdx.x;
    int s = srow & (SEQ - 1);
    int tok = tokens[srow];
    float val = 2.0f * 27.712812921102035f * emb[(size_t)tok * DM + d];
    int half2 = (d >> 1) * 2;
    float freq = expf(-(float)half2 * (9.210340371976184f / (float)DM));
    float ang = (float)s * freq;
    val += (d & 1) ? cosf(ang) : sinf(ang);
    x[(size_t)srow * DM + d] = val;
}

// ---------------- layernorm: fp32 in -> bf16 out ----------------
__global__ __launch_bounds__(256) void ln_k(const float* __restrict__ x,
                                            unsigned short* __restrict__ h,
                                            const float* __restrict__ alpha_p,
                                            const float* __restrict__ beta_p)
{
    int lane = threadIdx.x & 63;
    int wv = threadIdx.x >> 6;
    int row = blockIdx.x * 4 + wv;
    const float* xr = x + (size_t)row * DM;
    float4 v0 = *(const float4*)&xr[lane * 4];
    float4 v1 = *(const float4*)&xr[256 + lane * 4];
    float4 v2 = *(const float4*)&xr[512 + lane * 4];
    float s  = v0.x + v0.y + v0.z + v0.w + v1.x + v1.y + v1.z + v1.w
             + v2.x + v2.y + v2.z + v2.w;
    float sq = v0.x*v0.x + v0.y*v0.y + v0.z*v0.z + v0.w*v0.w
             + v1.x*v1.x + v1.y*v1.y + v1.z*v1.z + v1.w*v1.w
             + v2.x*v2.x + v2.y*v2.y + v2.z*v2.z + v2.w*v2.w;
#pragma unroll
    for (int m = 1; m < 64; m <<= 1) {
        s  += __shfl_xor(s, m);
        sq += __shfl_xor(sq, m);
    }
    float mean = s * (1.0f / DM);
    float var  = sq * (1.0f / DM) - mean * mean;
    float stdv = sqrtf(fmaxf(var, 0.0f));
    float scale = (*alpha_p) / (stdv + 1e-7f);
    float beta  = *beta_p;
    unsigned short* hr = h + (size_t)row * DM;
    ushort4 o;
    o.x = f2b((v0.x - mean) * scale + beta); o.y = f2b((v0.y - mean) * scale + beta);
    o.z = f2b((v0.z - mean) * scale + beta); o.w = f2b((v0.w - mean) * scale + beta);
    *(ushort4*)&hr[lane * 4] = o;
    o.x = f2b((v1.x - mean) * scale + beta); o.y = f2b((v1.y - mean) * scale + beta);
    o.z = f2b((v1.z - mean) * scale + beta); o.w = f2b((v1.w - mean) * scale + beta);
    *(ushort4*)&hr[256 + lane * 4] = o;
    o.x = f2b((v2.x - mean) * scale + beta); o.y = f2b((v2.y - mean) * scale + beta);
    o.z = f2b((v2.z - mean) * scale + beta); o.w = f2b((v2.w - mean) * scale + beta);
    *(ushort4*)&hr[512 + lane * 4] = o;
}

// ---------------- weight transpose-convert (one dispatch per layer) -----------
// fp32 [K][N] -> bf16 [N][K] for all 6 matrices of one layer.
struct WCAll { const float* src[6]; unsigned short* dst[6]; };
__global__ __launch_bounds__(256) void wconv_all_k(WCAll p)
{
    int t = blockIdx.x;
    const float* W; unsigned short* Wt; int K, N, bn, bk;
    if (t < 2304) {
        int mat = t / 576, rem = t % 576;
        W = p.src[mat]; Wt = p.dst[mat]; K = 768; N = 768;
        bn = (rem % 24) * 32; bk = (rem / 24) * 32;
    } else if (t < 4608) {
        int rem = t - 2304;
        W = p.src[4]; Wt = p.dst[4]; K = 768; N = 3072;
        bn = (rem % 96) * 32; bk = (rem / 96) * 32;
    } else {
        int rem = t - 4608;
        W = p.src[5]; Wt = p.dst[5]; K = 3072; N = 768;
        bn = (rem % 24) * 32; bk = (rem / 24) * 32;
    }
    __shared__ float tt[32][33];
    int tx = threadIdx.x & 31, ty = threadIdx.x >> 5;
#pragma unroll
    for (int i = 0; i < 4; ++i)
        tt[ty * 4 + i][tx] = W[(size_t)(bk + ty * 4 + i) * N + bn + tx];
    __syncthreads();
    int n_l = threadIdx.x >> 3;
    int k_l = (threadIdx.x & 7) * 4;
    ushort4 o;
    o.x = f2b(tt[k_l + 0][n_l]); o.y = f2b(tt[k_l + 1][n_l]);
    o.z = f2b(tt[k_l + 2][n_l]); o.w = f2b(tt[k_l + 3][n_l]);
    *(ushort4*)&Wt[(size_t)(bn + n_l) * K + bk + k_l] = o;
}

// ---------------- bf16 MFMA GEMM ----------------
// A: bf16 [M][K] row-major; Bt: bf16 [N][K] row-major (B transposed).
// 128x128 tile, BK=64, 4 waves (2x2), wave tile 64x64 = 4x4 fragments 16x16.
// OUT_MODE: 1 = fp32 resid add, 2 = bf16 relu store, 3 = bf16 store,
//           4 = bf16 transposed V store (Vt[b][h][d][s]), 5 = fp32 atomicAdd (split-K)
template<int OUT_MODE>
__device__ __forceinline__ void gemm_mfma_body(
    const unsigned short* __restrict__ A,
    const unsigned short* __restrict__ Bt,
    const float* __restrict__ bias,
    void* __restrict__ Cv,
    int N, int K, int kbeg, int kend, int bm, int bn)
{
    __shared__ unsigned short As[128][64];
    __shared__ unsigned short Bs[128][64];
    const int tid = threadIdx.x;
    const int lane = tid & 63;
    const int w = tid >> 6;
    const int wm = (w >> 1) << 6;
    const int wn = (w & 1) << 6;
    const int rgrp = lane >> 3;
    const int chunk = (lane & 7) ^ rgrp;
    const size_t a_src = (size_t)(bm + w * 32 + rgrp) * K + chunk * 8;
    const size_t b_src = (size_t)(bn + w * 32 + rgrp) * K + chunk * 8;

    f32x4 acc[4][4] = {};

    for (int kt = kbeg; kt < kend; kt += 64) {
        __syncthreads();
#pragma unroll
        for (int i = 0; i < 4; ++i) {
            __builtin_amdgcn_global_load_lds(
                (const __attribute__((address_space(1))) void*)(A + a_src + (size_t)(i * 8) * K + kt),
                (__attribute__((address_space(3))) void*)&As[w * 32 + i * 8][0], 16, 0, 0);
            __builtin_amdgcn_global_load_lds(
                (const __attribute__((address_space(1))) void*)(Bt + b_src + (size_t)(i * 8) * K + kt),
                (__attribute__((address_space(3))) void*)&Bs[w * 32 + i * 8][0], 16, 0, 0);
        }
        __syncthreads();
#pragma unroll
        for (int kk = 0; kk < 2; ++kk) {
            bf16x8 af[4], bfr[4];
            const int kb = kk * 64 + ((lane >> 4) << 4);
#pragma unroll
            for (int i = 0; i < 4; ++i) {
                int m = wm + i * 16 + (lane & 15);
                af[i] = *(const bf16x8*)((const char*)&As[0][0] + m * 128 + (kb ^ ((m & 7) << 4)));
                int n = wn + i * 16 + (lane & 15);
                bfr[i] = *(const bf16x8*)((const char*)&Bs[0][0] + n * 128 + (kb ^ ((n & 7) << 4)));
            }
            __builtin_amdgcn_s_setprio(1);
#pragma unroll
            for (int i = 0; i < 4; ++i)
#pragma unroll
                for (int j = 0; j < 4; ++j)
                    acc[i][j] = __builtin_amdgcn_mfma_f32_16x16x32_bf16(af[i], bfr[j], acc[i][j], 0, 0, 0);
            __builtin_amdgcn_s_setprio(0);
        }
    }
    // epilogue: C/D layout col=lane&15, row=(lane>>4)*4+reg
    const int cl = lane & 15, rg = lane >> 4;
#pragma unroll
    for (int i = 0; i < 4; ++i) {
        int row0 = bm + wm + i * 16 + rg * 4;
#pragma unroll
        for (int j = 0; j < 4; ++j) {
            int col = bn + wn + j * 16 + cl;
            float bv = (OUT_MODE == 5 && kbeg > 0) ? 0.0f : bias[col];
            if (OUT_MODE == 4) {
                int bb = row0 >> 11;
                int s  = row0 & 2047;
                int hh = col >> 6, d = col & 63;
                ushort4 o;
                o.x = f2b(acc[i][j][0] + bv); o.y = f2b(acc[i][j][1] + bv);
                o.z = f2b(acc[i][j][2] + bv); o.w = f2b(acc[i][j][3] + bv);
                *(ushort4*)&((unsigned short*)Cv)[(((size_t)(bb * 12 + hh) * 64 + d) << 11) + s] = o;
            } else {
#pragma unroll
                for (int r = 0; r < 4; ++r) {
                    float val = acc[i][j][r] + bv;
                    size_t idx = (size_t)(row0 + r) * N + col;
                    if (OUT_MODE == 2) {
                        ((unsigned short*)Cv)[idx] = f2b(fmaxf(val, 0.0f));
                    } else if (OUT_MODE == 3) {
                        ((unsigned short*)Cv)[idx] = f2b(val);
                    } else if (OUT_MODE == 5) {
                        atomicAdd(&((float*)Cv)[idx], val);
                    } else {
                        ((float*)Cv)[idx] += val;
                    }
                }
            }
        }
    }
}

template<int OUT_MODE>
__global__ __launch_bounds__(256) void gemm_b(const unsigned short* __restrict__ A,
                                              const unsigned short* __restrict__ Bt,
                                              const float* __restrict__ bias,
                                              void* __restrict__ C, int N, int K)
{
    gemm_mfma_body<OUT_MODE>(A, Bt, bias, C, N, K, 0, K, blockIdx.y * 128, blockIdx.x * 128);
}

// split-K=2, fp32 atomicAdd into C (C pre-loaded with residual)
__global__ __launch_bounds__(256) void gemm_sk(const unsigned short* __restrict__ A,
                                               const unsigned short* __restrict__ Bt,
                                               const float* __restrict__ bias,
                                               float* __restrict__ C, int N, int K)
{
    int half = K >> 1;
    gemm_mfma_body<5>(A, Bt, bias, C, N, K, blockIdx.z * half, blockIdx.z * half + half,
                      blockIdx.y * 128, blockIdx.x * 128);
}

struct QKVArgsB {
    const unsigned short *wq, *wk, *wv;
    const float *bq, *bk, *bv;
    unsigned short *q, *k, *vt;
};
__global__ __launch_bounds__(256) void gemm_qkv_b(const unsigned short* __restrict__ h, QKVArgsB p)
{
    if (blockIdx.z == 0)
        gemm_mfma_body<3>(h, p.wq, p.bq, p.q, DM, DM, 0, DM, blockIdx.y * 128, blockIdx.x * 128);
    else if (blockIdx.z == 1)
        gemm_mfma_body<3>(h, p.wk, p.bk, p.k, DM, DM, 0, DM, blockIdx.y * 128, blockIdx.x * 128);
    else
        gemm_mfma_body<4>(h, p.wv, p.bv, p.vt, DM, DM, 0, DM, blockIdx.y * 128, blockIdx.x * 128);
}

// ---------------- MFMA flash attention (swapped QK^T, Qr=32/wave) ------------
// Grid (SEQ/128, NH, B); 4 waves; wave w owns q rows [w*32, w*32+32) (2 frags).
// S^T = mfma(K_frag, Q_frag): lane owns q-col = lane&15 per fragment.
#define SM_SCALE 0.18033688f     // 0.125 * log2(e)
#define DEFER_THR 8.0f
__global__ __launch_bounds__(256) void attn_m(const unsigned short* __restrict__ qg,
                                              const unsigned short* __restrict__ kg,
                                              const unsigned short* __restrict__ vt,
                                              unsigned short* __restrict__ og)
{
    __shared__ unsigned short Ks[2][64 * 64];    // [s][d] swizzled, double-buffered
    __shared__ unsigned short Vs[2][64 * 64];    // [d][s] swizzled, double-buffered
    __shared__ unsigned short Ps[4 * 32 * 64];   // per-wave [q 32][s 64] swizzled
    const int tid = threadIdx.x;
    const int lane = tid & 63;
    const int w = tid >> 6;
    const int cl = lane & 15, g = lane >> 4;
    const int qt = blockIdx.x, h = blockIdx.y, b = blockIdx.z;
    const int qrow0 = (b << 11) + qt * 128;
    const int krow0 = (b << 11);
    const int srow8 = lane >> 3;
    const int c8 = (lane & 7) ^ srow8;
    const int swz = (cl & 7) << 4;

    // Q fragments (B-operand: col = q = cl, k = d); 2 q-fragments per wave
    bf16x8 qf[2][2];
#pragma unroll
    for (int mi = 0; mi < 2; ++mi)
#pragma unroll
        for (int sl = 0; sl < 2; ++sl)
            qf[mi][sl] = *(const bf16x8*)(qg + (size_t)(qrow0 + w * 32 + mi * 16 + cl) * DM
                                          + h * 64 + sl * 32 + g * 8);

    f32x4 oa[2][4] = {};
    float m_r[2] = { -3.0e38f, -3.0e38f };
    float l_r[2] = { 0.f, 0.f };                  // per-lane partials (reduced at end)

    const unsigned short* ksrc = kg + (size_t)(krow0 + w * 16 + srow8) * DM + h * 64 + c8 * 8;
    const unsigned short* vsrc = vt + ((size_t)((b * 12 + h) * 64) + w * 16 + srow8) * SEQ + c8 * 8;
    char* pbase = (char*)Ps + w * 4096;

#define STAGE(kt_, c_)                                                                         \
    {                                                                                          \
        _Pragma("unroll")                                                                      \
        for (int t = 0; t < 2; ++t) {                                                          \
            __builtin_amdgcn_global_load_lds(                                                  \
                (const __attribute__((address_space(1))) void*)(ksrc + (size_t)((kt_) * 64 + t * 8) * DM), \
                (__attribute__((address_space(3))) void*)&Ks[c_][(w * 16 + t * 8) * 64], 16, 0, 0);        \
            __builtin_amdgcn_global_load_lds(                                                  \
                (const __attribute__((address_space(1))) void*)(vsrc + (size_t)(t * 8) * SEQ + (kt_) * 64), \
                (__attribute__((address_space(3))) void*)&Vs[c_][(w * 16 + t * 8) * 64], 16, 0, 0);        \
        }                                                                                      \
    }

    STAGE(0, 0);
    __syncthreads();                              // drain vmcnt(0): tile 0 ready

    for (int kt = 0; kt < SEQ / 64; ++kt) {
        const int c = kt & 1;
        if (kt + 1 < SEQ / 64)
            STAGE(kt + 1, c ^ 1);                 // issue next tile early (T14)

        // S^T = K Q^T : rows s, cols q.  st[mi][ni] reg r <-> s = ni*16 + g*4 + r
        f32x4 st[2][4] = {};
#pragma unroll
        for (int sl = 0; sl < 2; ++sl) {
            bf16x8 kf[4];
#pragma unroll
            for (int ni = 0; ni < 4; ++ni) {
                int row = ni * 16 + cl;
                kf[ni] = *(const bf16x8*)((const char*)&Ks[c][0] + row * 128
                                          + ((sl * 64 + g * 16) ^ ((row & 7) << 4)));
            }
            __builtin_amdgcn_s_setprio(1);
#pragma unroll
            for (int mi = 0; mi < 2; ++mi)
#pragma unroll
                for (int ni = 0; ni < 4; ++ni)
                    st[mi][ni] = __builtin_amdgcn_mfma_f32_16x16x32_bf16(kf[ni], qf[mi][sl], st[mi][ni], 0, 0, 0);
            __builtin_amdgcn_s_setprio(0);
        }

#pragma unroll
        for (int mi = 0; mi < 2; ++mi) {
            // lane-local max (raw domain); cross-lane reduce only in rescale branch
            float pmax = st[mi][0][0];
#pragma unroll
            for (int ni = 0; ni < 4; ++ni)
#pragma unroll
                for (int r = 0; r < 4; ++r)
                    pmax = fmaxf(pmax, st[mi][ni][r]);

            if (!__all(pmax * SM_SCALE <= m_r[mi] + DEFER_THR)) {   // defer-max (T13)
                float mx = fmaxf(pmax, __shfl_xor(pmax, 16));
                mx = fmaxf(mx, __shfl_xor(mx, 32));
                mx *= SM_SCALE;
                float mnew = fmaxf(m_r[mi], mx);
                float sc = exp2f(m_r[mi] - mnew);
                l_r[mi] *= sc;
                m_r[mi] = mnew;
                float scr[4];
#pragma unroll
                for (int r = 0; r < 4; ++r)
                    scr[r] = __shfl(sc, g * 4 + r);   // q-col lane -> oa q-row
#pragma unroll
                for (int nj = 0; nj < 4; ++nj)
#pragma unroll
                    for (int r = 0; r < 4; ++r)
                        oa[mi][nj][r] *= scr[r];
            }

            float rs = 0.f;
            float p[4][4];
#pragma unroll
            for (int ni = 0; ni < 4; ++ni)
#pragma unroll
                for (int r = 0; r < 4; ++r) {
                    p[ni][r] = exp2f(fmaf(st[mi][ni][r], SM_SCALE, -m_r[mi]));
                    rs += p[ni][r];
                }
            l_r[mi] += rs;                         // per-lane partial; no shfl here

            // pack P -> wave-private LDS via v_cvt_pk_bf16_f32 (T12 recipe)
            const int prow = mi * 16 + cl;
#pragma unroll
            for (int ni = 0; ni < 4; ++ni) {
                uint2 o2;
                o2.x = cvtpk2(p[ni][0], p[ni][1]);
                o2.y = cvtpk2(p[ni][2], p[ni][3]);
                *(uint2*)(pbase + prow * 128 + ((ni * 32 + g * 8) ^ swz)) = o2;
            }
        }
        asm volatile("" ::: "memory");            // keep P writes before PV reads

        // O += P V  (rows q, cols d)
#pragma unroll
        for (int ks = 0; ks < 2; ++ks) {
            bf16x8 pa[2], vb[4];
#pragma unroll
            for (int mi = 0; mi < 2; ++mi)
                pa[mi] = *(const bf16x8*)(pbase + (mi * 16 + cl) * 128 + ((ks * 64 + g * 16) ^ swz));
#pragma unroll
            for (int nj = 0; nj < 4; ++nj) {
                int row = nj * 16 + cl;
                vb[nj] = *(const bf16x8*)((const char*)&Vs[c][0] + row * 128
                                          + ((ks * 64 + g * 16) ^ ((row & 7) << 4)));
            }
            __builtin_amdgcn_s_setprio(1);
#pragma unroll
            for (int mi = 0; mi < 2; ++mi)
#pragma unroll
                for (int nj = 0; nj < 4; ++nj)
                    oa[mi][nj] = __builtin_amdgcn_mfma_f32_16x16x32_bf16(pa[mi], vb[nj], oa[mi][nj], 0, 0, 0);
            __builtin_amdgcn_s_setprio(0);
        }

        __syncthreads();   // drains vmcnt(0): next tile staged; buffers swappable
    }
#undef STAGE

    // epilogue: reduce per-lane l partials once, then normalize + store
#pragma unroll
    for (int mi = 0; mi < 2; ++mi) {
        float ls = l_r[mi];
        ls += __shfl_xor(ls, 16);
        ls += __shfl_xor(ls, 32);
        float linv[4];
#pragma unroll
        for (int r = 0; r < 4; ++r)
            linv[r] = 1.0f / __shfl(ls, g * 4 + r);
#pragma unroll
        for (int r = 0; r < 4; ++r) {
            int row = qrow0 + w * 32 + mi * 16 + g * 4 + r;
#pragma unroll
            for (int nj = 0; nj < 4; ++nj)
                og[(size_t)row * DM + h * 64 + nj * 16 + cl] = f2b(oa[mi][nj][r] * linv[r]);
        }
    }
}

// ---------------- host orchestration ----------------
extern "C" void kernel_launch(void* const* d_in, const int* in_sizes, int n_in,
                              void* d_out, int out_size, void* d_ws, size_t ws_size,
                              hipStream_t stream)
{
    const int*   tokens = (const int*)d_in[0];
    const float* emb    = (const float*)d_in[1];
    const float* Wq     = (const float*)d_in[2];
    const float* bq     = (const float*)d_in[3];
    const float* Wk     = (const float*)d_in[4];
    const float* bk     = (const float*)d_in[5];
    const float* Wv     = (const float*)d_in[6];
    const float* bv     = (const float*)d_in[7];
    const float* Wo     = (const float*)d_in[8];
    const float* bo     = (const float*)d_in[9];
    const float* W1     = (const float*)d_in[10];
    const float* b1     = (const float*)d_in[11];
    const float* W2     = (const float*)d_in[12];
    const float* b2     = (const float*)d_in[13];
    const float* ln_a   = (const float*)d_in[14];
    const float* ln_b   = (const float*)d_in[15];

    float* x = (float*)d_out;
    unsigned short* wq_b = (unsigned short*)d_ws;        // [768][768] bf16 (transposed)
    unsigned short* wk_b = wq_b + 589824;
    unsigned short* wv_b = wk_b + 589824;
    unsigned short* wo_b = wv_b + 589824;
    unsigned short* w1_b = wo_b + 589824;                // [3072][768]
    unsigned short* w2_b = w1_b + 2359296;               // [768][3072]
    unsigned short* h_b  = w2_b + 2359296;               // [4096][768]
    unsigned short* ob_b = h_b + 3145728;                // [4096][768]
    unsigned short* ff_b = ob_b + 3145728;               // [4096][3072]
    unsigned short* q_bf = ff_b + 12582912;              // [4096][768]
    unsigned short* k_bf = q_bf + 3145728;               // [4096][768]
    unsigned short* vt_b = k_bf + 3145728;               // [2][12][64][2048]

    embed_k<<<dim3(DM / 256, NTOK), 256, 0, stream>>>(tokens, emb, x);

    for (int l = 0; l < NL; ++l) {
        const size_t wsq = (size_t)l * DM * DM;
        const size_t wsf = (size_t)l * DM * DFF;

        WCAll wc;
        wc.src[0] = Wq + wsq; wc.src[1] = Wk + wsq; wc.src[2] = Wv + wsq;
        wc.src[3] = Wo + wsq; wc.src[4] = W1 + wsf; wc.src[5] = W2 + wsf;
        wc.dst[0] = wq_b; wc.dst[1] = wk_b; wc.dst[2] = wv_b;
        wc.dst[3] = wo_b; wc.dst[4] = w1_b; wc.dst[5] = w2_b;
        wconv_all_k<<<6912, 256, 0, stream>>>(wc);

        ln_k<<<NTOK / 4, 256, 0, stream>>>(x, h_b, ln_a + l * 2 + 0, ln_b + l * 2 + 0);

        QKVArgsB p { wq_b, wk_b, wv_b, bq + l * DM, bk + l * DM, bv + l * DM,
                     q_bf, k_bf, vt_b };
        gemm_qkv_b<<<dim3(DM / 128, NTOK / 128, 3), 256, 0, stream>>>(h_b, p);

        attn_m<<<dim3(SEQ / 128, NH, 2), 256, 0, stream>>>(q_bf, k_bf, vt_b, ob_b);

        gemm_sk<<<dim3(DM / 128, NTOK / 128, 2), 256, 0, stream>>>(
            ob_b, wo_b, bo + l * DM, x, DM, DM);

        ln_k<<<NTOK / 4, 256, 0, stream>>>(x, h_b, ln_a + l * 2 + 1, ln_b + l * 2 + 1);

        gemm_b<2><<<dim3(DFF / 128, NTOK / 128), 256, 0, stream>>>(
            h_b, w1_b, b1 + l * DFF, ff_b, DFF, DM);

        gemm_sk<<<dim3(DM / 128, NTOK / 128, 2), 256, 0, stream>>>(
            ff_b, w2_b, b2 + l * DM, x, DM, DFF);
    }
}

// Round 7
// 1250.819 us; speedup vs baseline: 1.1021x; 1.1021x over previous
//
#include <hip/hip_runtime.h>
#include <cstdint>

#define SEQ 2048
#define DM 768
#define NH 12
#define DKH 64
#define DFF 3072
#define NL 6
#define NTOK 4096   // B*S

typedef __attribute__((ext_vector_type(8))) short bf16x8;
typedef __attribute__((ext_vector_type(4))) float f32x4;

static __device__ __forceinline__ unsigned short f2b(float f) {
    unsigned int u = __builtin_bit_cast(unsigned int, f);
    unsigned int lsb = (u >> 16) & 1;
    u += 0x7fffu + lsb;                 // round-to-nearest-even
    return (unsigned short)(u >> 16);
}

static __device__ __forceinline__ unsigned int cvtpk2(float a, float b) {
    unsigned int r;
    asm("v_cvt_pk_bf16_f32 %0, %1, %2" : "=v"(r) : "v"(a), "v"(b));
    return r;                            // low16 = bf16(a), high16 = bf16(b)
}

// ---------------- embedding + positional encoding ----------------
__global__ __launch_bounds__(256) void embed_k(const int* __restrict__ tokens,
                                               const float* __restrict__ emb,
                                               float* __restrict__ x)
{
    int srow = blockIdx.y;
    int d = blockIdx.x * 256 + threadIdx.x;
    int s = srow & (SEQ - 1);
    int tok = tokens[srow];
    float val = 2.0f * 27.712812921102035f * emb[(size_t)tok * DM + d];
    int half2 = (d >> 1) * 2;
    float freq = expf(-(float)half2 * (9.210340371976184f / (float)DM));
    float ang = (float)s * freq;
    val += (d & 1) ? cosf(ang) : sinf(ang);
    x[(size_t)srow * DM + d] = val;
}

// ---------------- layernorm: fp32 in -> bf16 out ----------------
__global__ __launch_bounds__(256) void ln_k(const float* __restrict__ x,
                                            unsigned short* __restrict__ h,
                                            const float* __restrict__ alpha_p,
                                            const float* __restrict__ beta_p)
{
    int lane = threadIdx.x & 63;
    int wv = threadIdx.x >> 6;
    int row = blockIdx.x * 4 + wv;
    const float* xr = x + (size_t)row * DM;
    float4 v0 = *(const float4*)&xr[lane * 4];
    float4 v1 = *(const float4*)&xr[256 + lane * 4];
    float4 v2 = *(const float4*)&xr[512 + lane * 4];
    float s  = v0.x + v0.y + v0.z + v0.w + v1.x + v1.y + v1.z + v1.w
             + v2.x + v2.y + v2.z + v2.w;
    float sq = v0.x*v0.x + v0.y*v0.y + v0.z*v0.z + v0.w*v0.w
             + v1.x*v1.x + v1.y*v1.y + v1.z*v1.z + v1.w*v1.w
             + v2.x*v2.x + v2.y*v2.y + v2.z*v2.z + v2.w*v2.w;
#pragma unroll
    for (int m = 1; m < 64; m <<= 1) {
        s  += __shfl_xor(s, m);
        sq += __shfl_xor(sq, m);
    }
    float mean = s * (1.0f / DM);
    float var  = sq * (1.0f / DM) - mean * mean;
    float stdv = sqrtf(fmaxf(var, 0.0f));
    float scale = (*alpha_p) / (stdv + 1e-7f);
    float beta  = *beta_p;
    unsigned short* hr = h + (size_t)row * DM;
    ushort4 o;
    o.x = f2b((v0.x - mean) * scale + beta); o.y = f2b((v0.y - mean) * scale + beta);
    o.z = f2b((v0.z - mean) * scale + beta); o.w = f2b((v0.w - mean) * scale + beta);
    *(ushort4*)&hr[lane * 4] = o;
    o.x = f2b((v1.x - mean) * scale + beta); o.y = f2b((v1.y - mean) * scale + beta);
    o.z = f2b((v1.z - mean) * scale + beta); o.w = f2b((v1.w - mean) * scale + beta);
    *(ushort4*)&hr[256 + lane * 4] = o;
    o.x = f2b((v2.x - mean) * scale + beta); o.y = f2b((v2.y - mean) * scale + beta);
    o.z = f2b((v2.z - mean) * scale + beta); o.w = f2b((v2.w - mean) * scale + beta);
    *(ushort4*)&hr[512 + lane * 4] = o;
}

// ---------------- weight transpose-convert (one dispatch per layer) -----------
// fp32 [K][N] -> bf16 [N][K] for all 6 matrices of one layer.
struct WCAll { const float* src[6]; unsigned short* dst[6]; };
__global__ __launch_bounds__(256) void wconv_all_k(WCAll p)
{
    int t = blockIdx.x;
    const float* W; unsigned short* Wt; int K, N, bn, bk;
    if (t < 2304) {
        int mat = t / 576, rem = t % 576;
        W = p.src[mat]; Wt = p.dst[mat]; K = 768; N = 768;
        bn = (rem % 24) * 32; bk = (rem / 24) * 32;
    } else if (t < 4608) {
        int rem = t - 2304;
        W = p.src[4]; Wt = p.dst[4]; K = 768; N = 3072;
        bn = (rem % 96) * 32; bk = (rem / 96) * 32;
    } else {
        int rem = t - 4608;
        W = p.src[5]; Wt = p.dst[5]; K = 3072; N = 768;
        bn = (rem % 24) * 32; bk = (rem / 24) * 32;
    }
    __shared__ float tt[32][33];
    int tx = threadIdx.x & 31, ty = threadIdx.x >> 5;
#pragma unroll
    for (int i = 0; i < 4; ++i)
        tt[ty * 4 + i][tx] = W[(size_t)(bk + ty * 4 + i) * N + bn + tx];
    __syncthreads();
    int n_l = threadIdx.x >> 3;
    int k_l = (threadIdx.x & 7) * 4;
    ushort4 o;
    o.x = f2b(tt[k_l + 0][n_l]); o.y = f2b(tt[k_l + 1][n_l]);
    o.z = f2b(tt[k_l + 2][n_l]); o.w = f2b(tt[k_l + 3][n_l]);
    *(ushort4*)&Wt[(size_t)(bn + n_l) * K + bk + k_l] = o;
}

// ---------------- bf16 MFMA GEMM ----------------
// A: bf16 [M][K] row-major; Bt: bf16 [N][K] row-major (B transposed).
// 128x128 tile, BK=64, 4 waves (2x2), wave tile 64x64 = 4x4 fragments 16x16.
// OUT_MODE: 1 = fp32 resid add, 2 = bf16 relu store, 3 = bf16 store,
//           4 = bf16 transposed V store (Vt[b][h][d][s]), 5 = fp32 atomicAdd (split-K)
template<int OUT_MODE>
__device__ __forceinline__ void gemm_mfma_body(
    const unsigned short* __restrict__ A,
    const unsigned short* __restrict__ Bt,
    const float* __restrict__ bias,
    void* __restrict__ Cv,
    int N, int K, int kbeg, int kend, int bm, int bn)
{
    __shared__ unsigned short As[128][64];
    __shared__ unsigned short Bs[128][64];
    const int tid = threadIdx.x;
    const int lane = tid & 63;
    const int w = tid >> 6;
    const int wm = (w >> 1) << 6;
    const int wn = (w & 1) << 6;
    const int rgrp = lane >> 3;
    const int chunk = (lane & 7) ^ rgrp;
    const size_t a_src = (size_t)(bm + w * 32 + rgrp) * K + chunk * 8;
    const size_t b_src = (size_t)(bn + w * 32 + rgrp) * K + chunk * 8;

    f32x4 acc[4][4] = {};

    for (int kt = kbeg; kt < kend; kt += 64) {
        __syncthreads();
#pragma unroll
        for (int i = 0; i < 4; ++i) {
            __builtin_amdgcn_global_load_lds(
                (const __attribute__((address_space(1))) void*)(A + a_src + (size_t)(i * 8) * K + kt),
                (__attribute__((address_space(3))) void*)&As[w * 32 + i * 8][0], 16, 0, 0);
            __builtin_amdgcn_global_load_lds(
                (const __attribute__((address_space(1))) void*)(Bt + b_src + (size_t)(i * 8) * K + kt),
                (__attribute__((address_space(3))) void*)&Bs[w * 32 + i * 8][0], 16, 0, 0);
        }
        __syncthreads();
#pragma unroll
        for (int kk = 0; kk < 2; ++kk) {
            bf16x8 af[4], bfr[4];
            const int kb = kk * 64 + ((lane >> 4) << 4);
#pragma unroll
            for (int i = 0; i < 4; ++i) {
                int m = wm + i * 16 + (lane & 15);
                af[i] = *(const bf16x8*)((const char*)&As[0][0] + m * 128 + (kb ^ ((m & 7) << 4)));
                int n = wn + i * 16 + (lane & 15);
                bfr[i] = *(const bf16x8*)((const char*)&Bs[0][0] + n * 128 + (kb ^ ((n & 7) << 4)));
            }
            __builtin_amdgcn_s_setprio(1);
#pragma unroll
            for (int i = 0; i < 4; ++i)
#pragma unroll
                for (int j = 0; j < 4; ++j)
                    acc[i][j] = __builtin_amdgcn_mfma_f32_16x16x32_bf16(af[i], bfr[j], acc[i][j], 0, 0, 0);
            __builtin_amdgcn_s_setprio(0);
        }
    }
    // epilogue: C/D layout col=lane&15, row=(lane>>4)*4+reg
    const int cl = lane & 15, rg = lane >> 4;
#pragma unroll
    for (int i = 0; i < 4; ++i) {
        int row0 = bm + wm + i * 16 + rg * 4;
#pragma unroll
        for (int j = 0; j < 4; ++j) {
            int col = bn + wn + j * 16 + cl;
            float bv = (OUT_MODE == 5 && kbeg > 0) ? 0.0f : bias[col];
            if (OUT_MODE == 4) {
                int bb = row0 >> 11;
                int s  = row0 & 2047;
                int hh = col >> 6, d = col & 63;
                ushort4 o;
                o.x = f2b(acc[i][j][0] + bv); o.y = f2b(acc[i][j][1] + bv);
                o.z = f2b(acc[i][j][2] + bv); o.w = f2b(acc[i][j][3] + bv);
                *(ushort4*)&((unsigned short*)Cv)[(((size_t)(bb * 12 + hh) * 64 + d) << 11) + s] = o;
            } else {
#pragma unroll
                for (int r = 0; r < 4; ++r) {
                    float val = acc[i][j][r] + bv;
                    size_t idx = (size_t)(row0 + r) * N + col;
                    if (OUT_MODE == 2) {
                        ((unsigned short*)Cv)[idx] = f2b(fmaxf(val, 0.0f));
                    } else if (OUT_MODE == 3) {
                        ((unsigned short*)Cv)[idx] = f2b(val);
                    } else if (OUT_MODE == 5) {
                        atomicAdd(&((float*)Cv)[idx], val);
                    } else {
                        ((float*)Cv)[idx] += val;
                    }
                }
            }
        }
    }
}

// T1: bijective XCD swizzle over the (x,y) raster (requires nwg % 8 == 0).
static __device__ __forceinline__ void xcd_swz(int gx, int& bm, int& bn)
{
    int flat = blockIdx.y * gx + blockIdx.x;
    int nwg = gx * gridDim.y;
    int wg = (flat & 7) * (nwg >> 3) + (flat >> 3);
    bm = (wg / gx) * 128;
    bn = (wg % gx) * 128;
}

template<int OUT_MODE>
__global__ __launch_bounds__(256) void gemm_b(const unsigned short* __restrict__ A,
                                              const unsigned short* __restrict__ Bt,
                                              const float* __restrict__ bias,
                                              void* __restrict__ C, int N, int K)
{
    int bm, bn; xcd_swz(gridDim.x, bm, bn);
    gemm_mfma_body<OUT_MODE>(A, Bt, bias, C, N, K, 0, K, bm, bn);
}

// split-K=2, fp32 atomicAdd into C (C pre-loaded with residual)
__global__ __launch_bounds__(256) void gemm_sk(const unsigned short* __restrict__ A,
                                               const unsigned short* __restrict__ Bt,
                                               const float* __restrict__ bias,
                                               float* __restrict__ C, int N, int K)
{
    int bm, bn; xcd_swz(gridDim.x, bm, bn);
    int half = K >> 1;
    gemm_mfma_body<5>(A, Bt, bias, C, N, K, blockIdx.z * half, blockIdx.z * half + half,
                      bm, bn);
}

struct QKVArgsB {
    const unsigned short *wq, *wk, *wv;
    const float *bq, *bk, *bv;
    unsigned short *q, *k, *vt;
};
__global__ __launch_bounds__(256) void gemm_qkv_b(const unsigned short* __restrict__ h, QKVArgsB p)
{
    int bm, bn; xcd_swz(gridDim.x, bm, bn);
    if (blockIdx.z == 0)
        gemm_mfma_body<3>(h, p.wq, p.bq, p.q, DM, DM, 0, DM, bm, bn);
    else if (blockIdx.z == 1)
        gemm_mfma_body<3>(h, p.wk, p.bk, p.k, DM, DM, 0, DM, bm, bn);
    else
        gemm_mfma_body<4>(h, p.wv, p.bv, p.vt, DM, DM, 0, DM, bm, bn);
}

// ---------------- MFMA flash attention (swapped QK^T, dbuf K/V, l via ones) --
// Grid (SEQ/64, NH, B); 4 waves; wave w owns q rows [w*16, w*16+16).
// S^T = mfma(K_frag, Q_frag): lane owns q-col = lane&15, 16 s-values in regs.
// l computed by PV MFMA against a constant ones B-fragment (same layout as oa).
#define SM_SCALE 0.18033688f     // 0.125 * log2(e)
#define DEFER_THR 8.0f
__global__ __launch_bounds__(256) void attn_m(const unsigned short* __restrict__ qg,
                                              const unsigned short* __restrict__ kg,
                                              const unsigned short* __restrict__ vt,
                                              unsigned short* __restrict__ og)
{
    __shared__ unsigned short Ks[2][64 * 64];    // [s][d] swizzled, double-buffered
    __shared__ unsigned short Vs[2][64 * 64];    // [d][s] swizzled, double-buffered
    __shared__ unsigned short Ps[4 * 16 * 64];   // per-wave [q][s] swizzled
    const int tid = threadIdx.x;
    const int lane = tid & 63;
    const int w = tid >> 6;
    const int cl = lane & 15, g = lane >> 4;
    const int qt = blockIdx.x, h = blockIdx.y, b = blockIdx.z;
    const int qrow0 = (b << 11) + qt * 64;
    const int krow0 = (b << 11);
    const int srow8 = lane >> 3;
    const int c8 = (lane & 7) ^ srow8;
    const int swz = (cl & 7) << 4;

    // Q fragments (B-operand: col = q = cl, k = d)
    bf16x8 qf[2];
#pragma unroll
    for (int sl = 0; sl < 2; ++sl)
        qf[sl] = *(const bf16x8*)(qg + (size_t)(qrow0 + w * 16 + cl) * DM
                                  + h * 64 + sl * 32 + g * 8);

    bf16x8 ones;
#pragma unroll
    for (int j = 0; j < 8; ++j) ones[j] = (short)0x3F80;   // bf16 1.0

    f32x4 oa[4] = {};
    f32x4 la = {};                                // l accumulator (ones-column)
    float m_r = -3.0e38f;

    const unsigned short* ksrc = kg + (size_t)(krow0 + w * 16 + srow8) * DM + h * 64 + c8 * 8;
    const unsigned short* vsrc = vt + ((size_t)((b * 12 + h) * 64) + w * 16 + srow8) * SEQ + c8 * 8;
    char* pbase = (char*)Ps + w * 2048;

#define STAGE(kt_, c_)                                                                         \
    {                                                                                          \
        _Pragma("unroll")                                                                      \
        for (int t = 0; t < 2; ++t) {                                                          \
            __builtin_amdgcn_global_load_lds(                                                  \
                (const __attribute__((address_space(1))) void*)(ksrc + (size_t)((kt_) * 64 + t * 8) * DM), \
                (__attribute__((address_space(3))) void*)&Ks[c_][(w * 16 + t * 8) * 64], 16, 0, 0);        \
            __builtin_amdgcn_global_load_lds(                                                  \
                (const __attribute__((address_space(1))) void*)(vsrc + (size_t)(t * 8) * SEQ + (kt_) * 64), \
                (__attribute__((address_space(3))) void*)&Vs[c_][(w * 16 + t * 8) * 64], 16, 0, 0);        \
        }                                                                                      \
    }

    STAGE(0, 0);
    __syncthreads();                              // drain vmcnt(0): tile 0 ready

    for (int kt = 0; kt < SEQ / 64; ++kt) {
        const int c = kt & 1;
        if (kt + 1 < SEQ / 64)
            STAGE(kt + 1, c ^ 1);                 // issue next tile early (T14)

        // S^T = K Q^T : rows s, cols q.  st[ni] reg r <-> s = ni*16 + g*4 + r
        f32x4 st[4] = {};
#pragma unroll
        for (int sl = 0; sl < 2; ++sl) {
            bf16x8 kf[4];
#pragma unroll
            for (int ni = 0; ni < 4; ++ni) {
                int row = ni * 16 + cl;
                kf[ni] = *(const bf16x8*)((const char*)&Ks[c][0] + row * 128
                                          + ((sl * 64 + g * 16) ^ ((row & 7) << 4)));
            }
            __builtin_amdgcn_s_setprio(1);
#pragma unroll
            for (int ni = 0; ni < 4; ++ni)
                st[ni] = __builtin_amdgcn_mfma_f32_16x16x32_bf16(kf[ni], qf[sl], st[ni], 0, 0, 0);
            __builtin_amdgcn_s_setprio(0);
        }

        // in-register online softmax for q-col = cl (16 s-values per lane)
        float pmax = st[0][0];
#pragma unroll
        for (int ni = 0; ni < 4; ++ni)
#pragma unroll
            for (int r = 0; r < 4; ++r)
                pmax = fmaxf(pmax, st[ni][r]);

        if (!__all(pmax * SM_SCALE <= m_r + DEFER_THR)) {   // defer-max (T13)
            float mx = fmaxf(pmax, __shfl_xor(pmax, 16));
            mx = fmaxf(mx, __shfl_xor(mx, 32));
            mx *= SM_SCALE;
            float mnew = fmaxf(m_r, mx);
            float sc = exp2f(m_r - mnew);
            m_r = mnew;
            float scr[4];
#pragma unroll
            for (int r = 0; r < 4; ++r)
                scr[r] = __shfl(sc, g * 4 + r);   // q-col lane -> q-row broadcast
#pragma unroll
            for (int r = 0; r < 4; ++r) {
                la[r] *= scr[r];
#pragma unroll
                for (int nj = 0; nj < 4; ++nj)
                    oa[nj][r] *= scr[r];
            }
        }

        // P = exp2(S*scale - m), packed straight to LDS via v_cvt_pk_bf16_f32
#pragma unroll
        for (int ni = 0; ni < 4; ++ni) {
            float p0 = exp2f(fmaf(st[ni][0], SM_SCALE, -m_r));
            float p1 = exp2f(fmaf(st[ni][1], SM_SCALE, -m_r));
            float p2 = exp2f(fmaf(st[ni][2], SM_SCALE, -m_r));
            float p3 = exp2f(fmaf(st[ni][3], SM_SCALE, -m_r));
            uint2 o2;
            o2.x = cvtpk2(p0, p1);
            o2.y = cvtpk2(p2, p3);
            *(uint2*)(pbase + cl * 128 + ((ni * 32 + g * 8) ^ swz)) = o2;
        }
        asm volatile("" ::: "memory");            // keep P writes before PV reads

        // O += P V ; l += P 1  (rows q, cols d)
#pragma unroll
        for (int ks = 0; ks < 2; ++ks) {
            bf16x8 pa, vb[4];
            pa = *(const bf16x8*)(pbase + cl * 128 + ((ks * 64 + g * 16) ^ swz));
#pragma unroll
            for (int nj = 0; nj < 4; ++nj) {
                int row = nj * 16 + cl;
                vb[nj] = *(const bf16x8*)((const char*)&Vs[c][0] + row * 128
                                          + ((ks * 64 + g * 16) ^ ((row & 7) << 4)));
            }
            __builtin_amdgcn_s_setprio(1);
#pragma unroll
            for (int nj = 0; nj < 4; ++nj)
                oa[nj] = __builtin_amdgcn_mfma_f32_16x16x32_bf16(pa, vb[nj], oa[nj], 0, 0, 0);
            la = __builtin_amdgcn_mfma_f32_16x16x32_bf16(pa, ones, la, 0, 0, 0);
            __builtin_amdgcn_s_setprio(0);
        }

        __syncthreads();   // drains vmcnt(0): next tile staged; buffers swappable
    }
#undef STAGE

    // epilogue: la[r] = l for q-row g*4+r (all 16 cols equal) -> no shfl needed
#pragma unroll
    for (int r = 0; r < 4; ++r) {
        float linv = 1.0f / la[r];
        int row = qrow0 + w * 16 + g * 4 + r;
#pragma unroll
        for (int nj = 0; nj < 4; ++nj)
            og[(size_t)row * DM + h * 64 + nj * 16 + cl] = f2b(oa[nj][r] * linv);
    }
}

// ---------------- host orchestration ----------------
extern "C" void kernel_launch(void* const* d_in, const int* in_sizes, int n_in,
                              void* d_out, int out_size, void* d_ws, size_t ws_size,
                              hipStream_t stream)
{
    const int*   tokens = (const int*)d_in[0];
    const float* emb    = (const float*)d_in[1];
    const float* Wq     = (const float*)d_in[2];
    const float* bq     = (const float*)d_in[3];
    const float* Wk     = (const float*)d_in[4];
    const float* bk     = (const float*)d_in[5];
    const float* Wv     = (const float*)d_in[6];
    const float* bv     = (const float*)d_in[7];
    const float* Wo     = (const float*)d_in[8];
    const float* bo     = (const float*)d_in[9];
    const float* W1     = (const float*)d_in[10];
    const float* b1     = (const float*)d_in[11];
    const float* W2     = (const float*)d_in[12];
    const float* b2     = (const float*)d_in[13];
    const float* ln_a   = (const float*)d_in[14];
    const float* ln_b   = (const float*)d_in[15];

    float* x = (float*)d_out;
    unsigned short* wq_b = (unsigned short*)d_ws;        // [768][768] bf16 (transposed)
    unsigned short* wk_b = wq_b + 589824;
    unsigned short* wv_b = wk_b + 589824;
    unsigned short* wo_b = wv_b + 589824;
    unsigned short* w1_b = wo_b + 589824;                // [3072][768]
    unsigned short* w2_b = w1_b + 2359296;               // [768][3072]
    unsigned short* h_b  = w2_b + 2359296;               // [4096][768]
    unsigned short* ob_b = h_b + 3145728;                // [4096][768]
    unsigned short* ff_b = ob_b + 3145728;               // [4096][3072]
    unsigned short* q_bf = ff_b + 12582912;              // [4096][768]
    unsigned short* k_bf = q_bf + 3145728;               // [4096][768]
    unsigned short* vt_b = k_bf + 3145728;               // [2][12][64][2048]

    embed_k<<<dim3(DM / 256, NTOK), 256, 0, stream>>>(tokens, emb, x);

    for (int l = 0; l < NL; ++l) {
        const size_t wsq = (size_t)l * DM * DM;
        const size_t wsf = (size_t)l * DM * DFF;

        WCAll wc;
        wc.src[0] = Wq + wsq; wc.src[1] = Wk + wsq; wc.src[2] = Wv + wsq;
        wc.src[3] = Wo + wsq; wc.src[4] = W1 + wsf; wc.src[5] = W2 + wsf;
        wc.dst[0] = wq_b; wc.dst[1] = wk_b; wc.dst[2] = wv_b;
        wc.dst[3] = wo_b; wc.dst[4] = w1_b; wc.dst[5] = w2_b;
        wconv_all_k<<<6912, 256, 0, stream>>>(wc);

        ln_k<<<NTOK / 4, 256, 0, stream>>>(x, h_b, ln_a + l * 2 + 0, ln_b + l * 2 + 0);

        QKVArgsB p { wq_b, wk_b, wv_b, bq + l * DM, bk + l * DM, bv + l * DM,
                     q_bf, k_bf, vt_b };
        gemm_qkv_b<<<dim3(DM / 128, NTOK / 128, 3), 256, 0, stream>>>(h_b, p);

        attn_m<<<dim3(SEQ / 64, NH, 2), 256, 0, stream>>>(q_bf, k_bf, vt_b, ob_b);

        gemm_sk<<<dim3(DM / 128, NTOK / 128, 2), 256, 0, stream>>>(
            ob_b, wo_b, bo + l * DM, x, DM, DM);

        ln_k<<<NTOK / 4, 256, 0, stream>>>(x, h_b, ln_a + l * 2 + 1, ln_b + l * 2 + 1);

        gemm_b<2><<<dim3(DFF / 128, NTOK / 128), 256, 0, stream>>>(
            h_b, w1_b, b1 + l * DFF, ff_b, DFF, DM);

        gemm_sk<<<dim3(DM / 128, NTOK / 128, 2), 256, 0, stream>>>(
            ff_b, w2_b, b2 + l * DM, x, DM, DFF);
    }
}